// Round 2
// baseline (20297.296 us; speedup 1.0000x reference)
//
#include <hip/hip_runtime.h>
#include <hip/hip_bf16.h>

// CharRNN: embed -> 4x (LayerNorm-LSTM over T=128) -> projection to vocab.
// Round 1: fix recurrence precision via 3-term split-bf16 (hi/lo) MFMA for
// all recurrent-path matmuls; hoist x@Wx out of the sequential loop as a
// per-layer parallel GEMM (bias folded). Projection stays plain bf16.

typedef __bf16 bf16x8 __attribute__((ext_vector_type(8)));
typedef __bf16 bf16x4 __attribute__((ext_vector_type(4)));
typedef float  f32x4  __attribute__((ext_vector_type(4)));

#define VOCAB 32000
#define BATCH 32
#define SEQ   128
#define RNN   1024
#define NLAY  4

__device__ __forceinline__ float sigm(float x) { return 1.f / (1.f + __expf(-x)); }

// ---------------------------------------------------------------------------
// W [L][2048][4096] f32 -> Wt [L][2 planes (hi,lo)][4096][2048] bf16,
// transposed to [n][k] so MFMA B-fragments are contiguous 16B loads.
// k 0..1023 = x-part (Wx), k 1024..2047 = h-part (Wh).
__global__ __launch_bounds__(256) void k_cvt_w(const float* __restrict__ W,
                                               __bf16* __restrict__ Wt) {
    __shared__ float lds[64][65];
    const int tid = threadIdx.x, tx = tid & 15, ty = tid >> 4;
    const int n0 = blockIdx.x * 64, k0 = blockIdx.y * 64;
    const size_t l = blockIdx.z;
    const float* src = W + (l * 2048 + (size_t)k0) * 4096 + n0;
#pragma unroll
    for (int rr = 0; rr < 4; ++rr) {
        int kr = rr * 16 + ty;
        f32x4 v = *(const f32x4*)(src + (size_t)kr * 4096 + tx * 4);
        lds[kr][tx*4+0] = v[0]; lds[kr][tx*4+1] = v[1];
        lds[kr][tx*4+2] = v[2]; lds[kr][tx*4+3] = v[3];
    }
    __syncthreads();
    __bf16* dhi = Wt + ((l * 2 + 0) * 4096 + (size_t)n0) * 2048 + k0;
    __bf16* dlo = Wt + ((l * 2 + 1) * 4096 + (size_t)n0) * 2048 + k0;
#pragma unroll
    for (int rr = 0; rr < 4; ++rr) {
        int nr = rr * 16 + ty;
        bf16x4 ohi, olo;
#pragma unroll
        for (int j = 0; j < 4; ++j) {
            float x = lds[tx*4+j][nr];
            __bf16 h = (__bf16)x;
            ohi[j] = h;
            olo[j] = (__bf16)(x - (float)h);
        }
        *(bf16x4*)(dhi + (size_t)nr * 2048 + tx * 4) = ohi;
        *(bf16x4*)(dlo + (size_t)nr * 2048 + tx * 4) = olo;
    }
}

// plain f32 -> bf16 (hi only), 8 elems/thread, exact grid
__global__ __launch_bounds__(256) void k_cvt(const float* __restrict__ in,
                                             __bf16* __restrict__ out) {
    size_t i = ((size_t)blockIdx.x * 256 + threadIdx.x) * 8;
    f32x4 v0 = *(const f32x4*)(in + i);
    f32x4 v1 = *(const f32x4*)(in + i + 4);
    bf16x8 o;
    o[0]=(__bf16)v0[0]; o[1]=(__bf16)v0[1]; o[2]=(__bf16)v0[2]; o[3]=(__bf16)v0[3];
    o[4]=(__bf16)v1[0]; o[5]=(__bf16)v1[1]; o[6]=(__bf16)v1[2]; o[7]=(__bf16)v1[3];
    *(bf16x8*)(out + i) = o;
}

// embedding gather -> time-major [t*32+b][1024] hi/lo bf16
__global__ __launch_bounds__(256) void k_embed(const int* __restrict__ idx,
                                               const float* __restrict__ emb,
                                               __bf16* __restrict__ xhi,
                                               __bf16* __restrict__ xlo) {
    const int row = blockIdx.x;            // t*32 + b
    const int t = row >> 5, b = row & 31;
    const int id = idx[b * SEQ + t];
    const int tid = threadIdx.x;
    f32x4 v = *(const f32x4*)(emb + (size_t)id * RNN + tid * 4);
    bf16x4 hi, lo;
#pragma unroll
    for (int j = 0; j < 4; ++j) {
        __bf16 h = (__bf16)v[j];
        hi[j] = h; lo[j] = (__bf16)(v[j] - (float)h);
    }
    *(bf16x4*)(xhi + (size_t)row * RNN + tid * 4) = hi;
    *(bf16x4*)(xlo + (size_t)row * RNN + tid * 4) = lo;
}

// ---------------------------------------------------------------------------
// zx[4096][4096] = X @ Wx + bias, 3-term split bf16 MFMA (fp32-grade).
// Block = 64(M) x 64(N); wave = 4 m-tiles x 16 n.
__global__ __launch_bounds__(256) void k_xgemm(const __bf16* __restrict__ xhi,
                                               const __bf16* __restrict__ xlo,
                                               const __bf16* __restrict__ Wt, // layer base
                                               const float* __restrict__ bias,
                                               float* __restrict__ zx) {
    const int tid = threadIdx.x;
    const int lane = tid & 63, w = tid >> 6;
    const int g = lane >> 4, q = lane & 15;
    const int n = blockIdx.x * 64 + w * 16 + q;
    const int m0 = blockIdx.y * 64;
    const int ko = g * 8;
    const __bf16* bh = Wt + (size_t)n * 2048;              // hi plane, k in [0,1024)
    const __bf16* bl = Wt + ((size_t)4096 + n) * 2048;     // lo plane
    f32x4 acc[4] = {{0,0,0,0},{0,0,0,0},{0,0,0,0},{0,0,0,0}};
    const __bf16 *ah[4], *al[4];
#pragma unroll
    for (int mt = 0; mt < 4; ++mt) {
        int m = m0 + mt * 16 + q;
        ah[mt] = xhi + (size_t)m * RNN;
        al[mt] = xlo + (size_t)m * RNN;
    }
#pragma unroll 2
    for (int k0 = 0; k0 < RNN; k0 += 32) {
        bf16x8 bhf = *(const bf16x8*)(bh + k0 + ko);
        bf16x8 blf = *(const bf16x8*)(bl + k0 + ko);
#pragma unroll
        for (int mt = 0; mt < 4; ++mt) {
            bf16x8 ahf = *(const bf16x8*)(ah[mt] + k0 + ko);
            bf16x8 alf = *(const bf16x8*)(al[mt] + k0 + ko);
            acc[mt] = __builtin_amdgcn_mfma_f32_16x16x32_bf16(ahf, bhf, acc[mt], 0, 0, 0);
            acc[mt] = __builtin_amdgcn_mfma_f32_16x16x32_bf16(alf, bhf, acc[mt], 0, 0, 0);
            acc[mt] = __builtin_amdgcn_mfma_f32_16x16x32_bf16(ahf, blf, acc[mt], 0, 0, 0);
        }
    }
    const float bv = bias[n];
#pragma unroll
    for (int mt = 0; mt < 4; ++mt)
#pragma unroll
        for (int r = 0; r < 4; ++r) {
            int m = m0 + mt * 16 + g * 4 + r;
            zx[(size_t)m * 4096 + n] = acc[mt][r] + bv;
        }
}

// ---------------------------------------------------------------------------
// z[32,4096] = zx[t] + h_{t-1} @ Wh   (3-term split bf16 MFMA).
// 64 blocks x 4 waves; wave owns one 16-col tile, both 16-row tiles.
__global__ __launch_bounds__(256) void k_lstm_mm(const __bf16* __restrict__ hhi,
                                                 const __bf16* __restrict__ hlo,
                                                 const __bf16* __restrict__ Wt, // layer base
                                                 const float* __restrict__ zx,
                                                 float* __restrict__ z, int t) {
    const int tid = threadIdx.x;
    const int lane = tid & 63, w = tid >> 6;
    const int g = lane >> 4, q = lane & 15;
    const int n = blockIdx.x * 64 + w * 16 + q;
    const int ko = g * 8;
    f32x4 acc0 = {0.f,0.f,0.f,0.f}, acc1 = {0.f,0.f,0.f,0.f};
    if (t > 0) {   // h == 0 at t == 0
        const __bf16* bh = Wt + (size_t)n * 2048 + RNN;          // hi plane, k in [1024,2048)
        const __bf16* bl = Wt + ((size_t)4096 + n) * 2048 + RNN; // lo plane
        const __bf16* ah0 = hhi + (size_t)q * RNN;
        const __bf16* al0 = hlo + (size_t)q * RNN;
        const __bf16* ah1 = hhi + (size_t)(16 + q) * RNN;
        const __bf16* al1 = hlo + (size_t)(16 + q) * RNN;
#pragma unroll 2
        for (int k0 = 0; k0 < RNN; k0 += 32) {
            bf16x8 bhf = *(const bf16x8*)(bh + k0 + ko);
            bf16x8 blf = *(const bf16x8*)(bl + k0 + ko);
            bf16x8 a0h = *(const bf16x8*)(ah0 + k0 + ko);
            bf16x8 a0l = *(const bf16x8*)(al0 + k0 + ko);
            bf16x8 a1h = *(const bf16x8*)(ah1 + k0 + ko);
            bf16x8 a1l = *(const bf16x8*)(al1 + k0 + ko);
            acc0 = __builtin_amdgcn_mfma_f32_16x16x32_bf16(a0h, bhf, acc0, 0, 0, 0);
            acc0 = __builtin_amdgcn_mfma_f32_16x16x32_bf16(a0l, bhf, acc0, 0, 0, 0);
            acc0 = __builtin_amdgcn_mfma_f32_16x16x32_bf16(a0h, blf, acc0, 0, 0, 0);
            acc1 = __builtin_amdgcn_mfma_f32_16x16x32_bf16(a1h, bhf, acc1, 0, 0, 0);
            acc1 = __builtin_amdgcn_mfma_f32_16x16x32_bf16(a1l, bhf, acc1, 0, 0, 0);
            acc1 = __builtin_amdgcn_mfma_f32_16x16x32_bf16(a1h, blf, acc1, 0, 0, 0);
        }
    }
    const float* zxr = zx + ((size_t)t * BATCH) * 4096 + n;
#pragma unroll
    for (int r = 0; r < 4; ++r) {
        int row = g * 4 + r;
        z[(size_t)row * 4096 + n]        = acc0[r] + zxr[(size_t)row * 4096];
        z[(size_t)(row + 16) * 4096 + n] = acc1[r] + zxr[(size_t)(row + 16) * 4096];
    }
}

// ---------------------------------------------------------------------------
// Per-batch-row LN + gates + state update. One block per batch row b.
// Writes h (hi/lo) and the next layer's input row (hi/lo, in place over xs).
__global__ __launch_bounds__(256) void k_lstm_gates(const float* __restrict__ z,
                                                    float* __restrict__ c,
                                                    __bf16* __restrict__ hhi,
                                                    __bf16* __restrict__ hlo,
                                                    __bf16* __restrict__ xhi,
                                                    __bf16* __restrict__ xlo,
                                                    const float* __restrict__ g5,
                                                    const float* __restrict__ b5,
                                                    int t) {
    __shared__ float red[4][8];
    const int b = blockIdx.x, tid = threadIdx.x;
    const int lane = tid & 63, wv = tid >> 6;
    const f32x4* zr = (const f32x4*)(z + (size_t)b * 4096);
    f32x4 zi = zr[tid], zj = zr[256 + tid], zf = zr[512 + tid], zo = zr[768 + tid];

    float s[8];
    s[0] = zi[0]+zi[1]+zi[2]+zi[3];
    s[1] = zi[0]*zi[0]+zi[1]*zi[1]+zi[2]*zi[2]+zi[3]*zi[3];
    s[2] = zj[0]+zj[1]+zj[2]+zj[3];
    s[3] = zj[0]*zj[0]+zj[1]*zj[1]+zj[2]*zj[2]+zj[3]*zj[3];
    s[4] = zf[0]+zf[1]+zf[2]+zf[3];
    s[5] = zf[0]*zf[0]+zf[1]*zf[1]+zf[2]*zf[2]+zf[3]*zf[3];
    s[6] = zo[0]+zo[1]+zo[2]+zo[3];
    s[7] = zo[0]*zo[0]+zo[1]*zo[1]+zo[2]*zo[2]+zo[3]*zo[3];
#pragma unroll
    for (int o = 32; o; o >>= 1)
#pragma unroll
        for (int i = 0; i < 8; ++i) s[i] += __shfl_xor(s[i], o);
    if (lane == 0) {
#pragma unroll
        for (int i = 0; i < 8; ++i) red[wv][i] = s[i];
    }
    __syncthreads();
    float tot[8];
#pragma unroll
    for (int i = 0; i < 8; ++i) tot[i] = red[0][i]+red[1][i]+red[2][i]+red[3][i];

    const float inv = 1.f / (float)RNN;
    float mi = tot[0]*inv, ri = rsqrtf(tot[1]*inv - mi*mi + 1e-5f);
    float mj = tot[2]*inv, rj = rsqrtf(tot[3]*inv - mj*mj + 1e-5f);
    float mf = tot[4]*inv, rf = rsqrtf(tot[5]*inv - mf*mf + 1e-5f);
    float mo = tot[6]*inv, ro = rsqrtf(tot[7]*inv - mo*mo + 1e-5f);

    f32x4 gi = *(const f32x4*)(g5 + 0*RNN + tid*4), bi = *(const f32x4*)(b5 + 0*RNN + tid*4);
    f32x4 gj = *(const f32x4*)(g5 + 1*RNN + tid*4), bj = *(const f32x4*)(b5 + 1*RNN + tid*4);
    f32x4 gf = *(const f32x4*)(g5 + 2*RNN + tid*4), bfv= *(const f32x4*)(b5 + 2*RNN + tid*4);
    f32x4 go = *(const f32x4*)(g5 + 3*RNN + tid*4), bo = *(const f32x4*)(b5 + 3*RNN + tid*4);

    f32x4 cold = {0.f, 0.f, 0.f, 0.f};
    if (t > 0) cold = *(const f32x4*)(c + (size_t)b * RNN + tid * 4);

    f32x4 cnew, onrm;
    float cs = 0.f, cq = 0.f;
#pragma unroll
    for (int j = 0; j < 4; ++j) {
        float iv = (zi[j]-mi)*ri*gi[j] + bi[j];
        float jv = (zj[j]-mj)*rj*gj[j] + bj[j];
        float fv = (zf[j]-mf)*rf*gf[j] + bfv[j];
        float ov = (zo[j]-mo)*ro*go[j] + bo[j];
        float cc = cold[j] * sigm(fv + 1.0f) + sigm(iv) * tanhf(jv);
        cnew[j] = cc; onrm[j] = ov;
        cs += cc; cq += cc*cc;
    }
    *(f32x4*)(c + (size_t)b * RNN + tid * 4) = cnew;

    __syncthreads();   // protect red[] reuse
    float s2a = cs, s2b = cq;
#pragma unroll
    for (int o = 32; o; o >>= 1) { s2a += __shfl_xor(s2a, o); s2b += __shfl_xor(s2b, o); }
    if (lane == 0) { red[wv][0] = s2a; red[wv][1] = s2b; }
    __syncthreads();
    float mc = (red[0][0]+red[1][0]+red[2][0]+red[3][0]) * inv;
    float vc = (red[0][1]+red[1][1]+red[2][1]+red[3][1]) * inv - mc*mc;
    float rc = rsqrtf(vc + 1e-5f);

    f32x4 g4 = *(const f32x4*)(g5 + 4*RNN + tid*4);
    f32x4 b4 = *(const f32x4*)(b5 + 4*RNN + tid*4);
    bf16x4 hh, hl;
#pragma unroll
    for (int j = 0; j < 4; ++j) {
        float cn = (cnew[j]-mc)*rc*g4[j] + b4[j];
        float h = tanhf(cn) * sigm(onrm[j]);
        __bf16 a = (__bf16)h;
        hh[j] = a; hl[j] = (__bf16)(h - (float)a);
    }
    *(bf16x4*)(hhi + (size_t)b * RNN + tid * 4) = hh;
    *(bf16x4*)(hlo + (size_t)b * RNN + tid * 4) = hl;
    *(bf16x4*)(xhi + ((size_t)t * BATCH + b) * RNN + tid * 4) = hh;
    *(bf16x4*)(xlo + ((size_t)t * BATCH + b) * RNN + tid * 4) = hl;
}

// ---------------------------------------------------------------------------
// logits[m][v] = sum_k h[m][k]*smw[v][k] + smb[v], m = b*128+t; plain bf16.
// Source row in time-major buffer = (m&127)*32 + (m>>7).
__global__ __launch_bounds__(256) void k_proj(const __bf16* __restrict__ xs,
                                              const __bf16* __restrict__ wv,
                                              const float* __restrict__ sb,
                                              float* __restrict__ out) {
    const int tid = threadIdx.x;
    const int lane = tid & 63, w = tid >> 6;
    const int g = lane >> 4, q = lane & 15;
    const int n = blockIdx.x * 64 + w * 16 + q;
    const int m0 = blockIdx.y * 64;
    const int ko = g * 8;
    f32x4 acc[4] = {{0,0,0,0},{0,0,0,0},{0,0,0,0},{0,0,0,0}};
    const __bf16* arow[4];
#pragma unroll
    for (int mt = 0; mt < 4; ++mt) {
        int m = m0 + mt * 16 + q;
        arow[mt] = xs + (size_t)((m & 127) * 32 + (m >> 7)) * RNN;
    }
    const __bf16* brow = wv + (size_t)n * RNN;
#pragma unroll 2
    for (int k0 = 0; k0 < RNN; k0 += 32) {
        bf16x8 bfr = *(const bf16x8*)(brow + k0 + ko);
#pragma unroll
        for (int mt = 0; mt < 4; ++mt) {
            bf16x8 afr = *(const bf16x8*)(arow[mt] + k0 + ko);
            acc[mt] = __builtin_amdgcn_mfma_f32_16x16x32_bf16(afr, bfr, acc[mt], 0, 0, 0);
        }
    }
    const float bv = sb[n];
#pragma unroll
    for (int mt = 0; mt < 4; ++mt)
#pragma unroll
        for (int r = 0; r < 4; ++r) {
            int m = m0 + mt * 16 + g * 4 + r;
            out[(size_t)m * VOCAB + n] = acc[mt][r] + bv;
        }
}

// ---------------------------------------------------------------------------
extern "C" void kernel_launch(void* const* d_in, const int* in_sizes, int n_in,
                              void* d_out, int out_size, void* d_ws, size_t ws_size,
                              hipStream_t stream) {
    const int*   input = (const int*)  d_in[0];
    const float* emb   = (const float*)d_in[1];
    const float* W     = (const float*)d_in[2];
    const float* bias  = (const float*)d_in[3];
    const float* ln_g  = (const float*)d_in[4];
    const float* ln_b  = (const float*)d_in[5];
    const float* smw   = (const float*)d_in[6];
    const float* smb   = (const float*)d_in[7];
    float* out = (float*)d_out;

    char* p = (char*)d_ws;
    auto alloc = [&](size_t bytes) { char* r = p; p += (bytes + 255) & ~(size_t)255; return r; };
    __bf16* Wt   = (__bf16*)alloc((size_t)NLAY * 2 * 4096 * 2048 * 2); // 134.2 MB (hi+lo)
    __bf16* smwb = (__bf16*)alloc((size_t)VOCAB * RNN * 2);            // 65.5 MB
    __bf16* xhi  = (__bf16*)alloc((size_t)SEQ * BATCH * RNN * 2);      // 8.4 MB
    __bf16* xlo  = (__bf16*)alloc((size_t)SEQ * BATCH * RNN * 2);      // 8.4 MB
    float*  zx   = (float*) alloc((size_t)SEQ * BATCH * 4096 * 4);     // 67.1 MB
    float*  z    = (float*) alloc((size_t)BATCH * 4096 * 4);           // 512 KB
    __bf16* hhi  = (__bf16*)alloc((size_t)BATCH * RNN * 2);            // 64 KB
    __bf16* hlo  = (__bf16*)alloc((size_t)BATCH * RNN * 2);            // 64 KB
    float*  c    = (float*) alloc((size_t)BATCH * RNN * 4);            // 128 KB

    k_cvt_w<<<dim3(64, 32, NLAY), 256, 0, stream>>>(W, Wt);
    k_cvt<<<(VOCAB * RNN) / (8 * 256), 256, 0, stream>>>(smw, smwb);
    k_embed<<<SEQ * BATCH, 256, 0, stream>>>(input, emb, xhi, xlo);

    for (int l = 0; l < NLAY; ++l) {
        const __bf16* Wl  = Wt + (size_t)l * 2 * 4096 * 2048;
        const float*  bl  = bias + (size_t)l * 4096;
        const float*  gl  = ln_g + (size_t)l * 5 * RNN;
        const float*  bbl = ln_b + (size_t)l * 5 * RNN;
        // x-part for all timesteps (parallel GEMM, bias folded); consumes xs,
        // after which the t-loop overwrites xs rows in place with this
        // layer's h (the next layer's input).
        k_xgemm<<<dim3(64, 64), 256, 0, stream>>>(xhi, xlo, Wl, bl, zx);
        for (int t = 0; t < SEQ; ++t) {
            k_lstm_mm<<<64, 256, 0, stream>>>(hhi, hlo, Wl, zx, z, t);
            k_lstm_gates<<<BATCH, 256, 0, stream>>>(z, c, hhi, hlo, xhi, xlo, gl, bbl, t);
        }
    }
    // after l=3, final layer output (bf16 hi) lives in xhi (time-major)
    k_proj<<<dim3(VOCAB / 64, 4096 / 64), 256, 0, stream>>>(xhi, smwb, smb, out);
}